// Round 9
// baseline (418.692 us; speedup 1.0000x reference)
//
#include <hip/hip_runtime.h>
#include <hip/hip_bf16.h>
#include <stdint.h>

// ---------- types ----------
typedef __attribute__((ext_vector_type(8))) __bf16 bf16x8;
typedef __attribute__((ext_vector_type(4))) float f32x4;
typedef __attribute__((ext_vector_type(8))) unsigned short ushort8;

typedef const void __attribute__((address_space(1))) gv_t;
typedef void __attribute__((address_space(3))) lv_t;

#define GL16(g, l) __builtin_amdgcn_global_load_lds((gv_t*)(g), (lv_t*)(l), 16, 0, 0)

__device__ __forceinline__ unsigned short f2bf(float f) {
    unsigned int u = __float_as_uint(f);
    u += 0x7fffu + ((u >> 16) & 1u);
    return (unsigned short)(u >> 16);
}

// ---------- kernel 1: per-group int4 quant-dequant of W -> bf16 bits ----------
__global__ void __launch_bounds__(256) qdq_weight(const float* __restrict__ w,
                                                  unsigned short* __restrict__ wb,
                                                  int n_groups) {
    int g = blockIdx.x * 256 + threadIdx.x;
    if (g >= n_groups) return;
    const float4* p = (const float4*)w + (size_t)g * 2;
    float4 v0 = p[0], v1 = p[1];
    float t[8] = {v0.x, v0.y, v0.z, v0.w, v1.x, v1.y, v1.z, v1.w};
    float amax = 0.0f;
#pragma unroll
    for (int j = 0; j < 8; ++j) amax = fmaxf(amax, fabsf(t[j]));
    float scale = fmaxf(amax / 7.0f, 1e-8f);
    ushort8 o;
#pragma unroll
    for (int j = 0; j < 8; ++j) {
        float q = rintf(t[j] / scale);
        q = fminf(fmaxf(q, -7.0f), 7.0f);
        o[j] = f2bf(q * scale);
    }
    *((ushort8*)wb + g) = o;
}

// ---------- kernel 2: f32 -> bf16 cast of x ----------
__global__ void __launch_bounds__(256) cvt_bf16(const float* __restrict__ x,
                                                unsigned short* __restrict__ xb,
                                                int n8) {
    int i = blockIdx.x * 256 + threadIdx.x;
    if (i >= n8) return;
    const float4* p = (const float4*)x + (size_t)i * 2;
    float4 v0 = p[0], v1 = p[1];
    ushort8 o;
    o[0] = f2bf(v0.x); o[1] = f2bf(v0.y); o[2] = f2bf(v0.z); o[3] = f2bf(v0.w);
    o[4] = f2bf(v1.x); o[5] = f2bf(v1.y); o[6] = f2bf(v1.z); o[7] = f2bf(v1.w);
    *((ushort8*)xb + i) = o;
}

// ---------- kernel 3: 256x256 8-wave GEMM, A via LDS, B direct-to-register ----
// LDS-port relief: per K-tile/CU traffic drops 256KB -> 80KB (A reads+writes
// only). B frags (4/wave, 16B/lane, K-major) load global->VGPR one tile ahead;
// B panel (2MB/block) is L2/L3-resident; compiler's register deps insert the
// B-wait. One barrier + one counted VM(4) per K-tile (stage issues before B
// loads; sched_barrier pins vm-issue order so VM(4) drains exactly the stage).
#define BM 256
#define BN 256
#define BK 32

#define BAR_() asm volatile("s_barrier" ::: "memory")
#define VM4_() asm volatile("s_waitcnt vmcnt(4)" ::: "memory")
#define SB_()  __builtin_amdgcn_sched_barrier(0)

// stage A K-tile (256 rows x 32) into buf b: 2 x GL16 per thread
#define STAGE_A2(b, kk)                                                        \
    {                                                                          \
        GL16(gA + (size_t)(srow) * K + (kk) + schunk,                          \
             &sA[b][(w * 16) * BK]);                                           \
        GL16(gA + (size_t)(128 + srow) * K + (kk) + schunk,                    \
             &sA[b][(128 + w * 16) * BK]);                                     \
    }

#define LOADB(dst, kk)                                                         \
    _Pragma("unroll")                                                          \
    for (int ni = 0; ni < 4; ++ni)                                             \
        dst[ni] = *(const bf16x8*)(gBn[ni] + (kk));

#define READ_A(b)                                                              \
    _Pragma("unroll")                                                          \
    for (int mi = 0; mi < 8; ++mi)                                             \
        af[mi] = *(const bf16x8*)&sA[b][(wr * 128 + mi * 16 + lr) * BK + ce];

#define MFMA_T(BF)                                                             \
    __builtin_amdgcn_s_setprio(1);                                             \
    _Pragma("unroll")                                                          \
    for (int ni = 0; ni < 4; ++ni)                                             \
        _Pragma("unroll")                                                      \
        for (int mi = 0; mi < 8; ++mi)                                         \
            acc[mi][ni] = __builtin_amdgcn_mfma_f32_16x16x32_bf16(             \
                af[mi], BF[ni], acc[mi][ni], 0, 0, 0);                         \
    __builtin_amdgcn_s_setprio(0);

__global__ void __launch_bounds__(512, 1)
gemmBD(const unsigned short* __restrict__ A,   // [M][K] bf16 bits (x)
       const unsigned short* __restrict__ B,   // [N][K] bf16 bits (w_deq)
       const float* __restrict__ bias,
       float* __restrict__ C,
       int M, int N, int K) {
    __shared__ unsigned short sA[2][BM * BK];   // 2 x 16 KB

    const int t  = threadIdx.x;
    const int w  = t >> 6;        // wave 0..7
    const int ln = t & 63;
    const int lr = ln & 15;
    const int lk = ln >> 4;
    const int wr = w >> 2;        // wave M index (128 rows)
    const int wc = w & 3;         // wave N index (64 cols)
    const int bcol = wc * 64;

    // T1: bijective XCD swizzle (gridDim.x = 512, % 8 == 0)
    const int nbn = N / BN;
    const int bid = blockIdx.x;
    const int swz = ((int)gridDim.x & 7) ? bid
                  : ((bid & 7) * ((int)gridDim.x >> 3) + (bid >> 3));
    const int m0 = (swz / nbn) * BM;
    const int n0 = (swz % nbn) * BN;

    const unsigned short* gA = A + (size_t)m0 * K;

    // B direct-load bases: lane (lr,lk) of frag ni reads
    // B[n0+bcol+ni*16+lr][kk + lk*8 .. +8]
    const unsigned short* gBn[4];
#pragma unroll
    for (int ni = 0; ni < 4; ++ni)
        gBn[ni] = B + (size_t)(n0 + bcol + ni * 16 + lr) * K + lk * 8;

    // staging coords (BK=32: 64B rows, 4 x 16B chunks; swizzle chunk^=(row>>2)&3)
    const int srow   = t >> 2;                                   // 0..127
    const int schunk = (((t & 3) ^ ((t >> 4) & 3)) << 3);        // elements

    // read chunk offset (row bits 2-3 == lr bits 2-3)
    const int ce = ((lk ^ ((lr >> 2) & 3)) << 3);                // elements

    f32x4 acc[8][4];
#pragma unroll
    for (int i = 0; i < 8; ++i)
#pragma unroll
        for (int j = 0; j < 4; ++j)
            acc[i][j] = (f32x4)(0.0f);

    bf16x8 af[8], b_a[4], b_b[4];

    const int NT = K / BK;   // 128, even

    // prologue: stage A tile0 -> buf0; load B tile0 -> b_a
    STAGE_A2(0, 0);
    SB_();
    LOADB(b_a, 0);
    SB_();
    VM4_();        // drains the 2 stage loads; leaves 4 B loads in flight
    BAR_();

    for (int tt = 0; tt < NT; tt += 2) {
        const int k1 = (tt + 1) * BK;          // always < K (NT even)
        const int k2 = (tt + 2) * BK;
        const bool st2 = (tt + 2 < NT);

        // ---- even tile tt: compute buf0/b_a; prefetch tt+1 -> buf1/b_b ----
        STAGE_A2(1, k1);
        SB_();
        LOADB(b_b, k1);
        SB_();
        READ_A(0);
        MFMA_T(b_a);
        VM4_();    // outstanding: stage(2)+B(4) -> drains stage; B stays
        BAR_();

        // ---- odd tile tt+1: compute buf1/b_b; prefetch tt+2 -> buf0/b_a ----
        if (st2) {
            STAGE_A2(0, k2);
            SB_();
            LOADB(b_a, k2);
            SB_();
        }
        READ_A(1);
        MFMA_T(b_b);
        VM4_();
        BAR_();
    }

    // epilogue: C/D layout col = lane&15, row = (lane>>4)*4 + reg
#pragma unroll
    for (int ni = 0; ni < 4; ++ni) {
        const int n = n0 + bcol + ni * 16 + lr;
        const float bv = bias[n];
#pragma unroll
        for (int mi = 0; mi < 8; ++mi) {
            const int m = m0 + wr * 128 + mi * 16 + lk * 4;
            f32x4 v = acc[mi][ni];
            C[(size_t)(m + 0) * N + n] = v[0] + bv;
            C[(size_t)(m + 1) * N + n] = v[1] + bv;
            C[(size_t)(m + 2) * N + n] = v[2] + bv;
            C[(size_t)(m + 3) * N + n] = v[3] + bv;
        }
    }
}

// ---------- launcher ----------
extern "C" void kernel_launch(void* const* d_in, const int* in_sizes, int n_in,
                              void* d_out, int out_size, void* d_ws, size_t ws_size,
                              hipStream_t stream) {
    const float* x    = (const float*)d_in[0];
    const float* wgt  = (const float*)d_in[1];
    const float* bias = (const float*)d_in[2];
    float* out        = (float*)d_out;

    const int dout = in_sizes[2];            // 4096
    const int din  = in_sizes[1] / dout;     // 4096
    const int M    = in_sizes[0] / din;      // 8192
    const int N    = dout, K = din;

    unsigned short* xb = (unsigned short*)d_ws;          // [M][K] bf16 bits
    unsigned short* wb = xb + (size_t)M * K;             // [N][K] bf16 bits

    const int ng_w = (N * K) / 8;
    qdq_weight<<<(ng_w + 255) / 256, 256, 0, stream>>>(wgt, wb, ng_w);

    const int n8_x = (M * K) / 8;
    cvt_bf16<<<(n8_x + 255) / 256, 256, 0, stream>>>(x, xb, n8_x);

    const int nwg = (M / BM) * (N / BN);     // 32 * 16 = 512, % 8 == 0
    gemmBD<<<nwg, 512, 0, stream>>>(xb, wb, bias, out, M, N, K);
}

// Round 10
// 322.152 us; speedup vs baseline: 1.2997x; 1.2997x over previous
//
#include <hip/hip_runtime.h>
#include <hip/hip_bf16.h>
#include <stdint.h>

// ---------- types ----------
typedef __attribute__((ext_vector_type(8))) __bf16 bf16x8;
typedef __attribute__((ext_vector_type(4))) float f32x4;
typedef __attribute__((ext_vector_type(16))) float f32x16;
typedef __attribute__((ext_vector_type(8))) unsigned short ushort8;

typedef const void __attribute__((address_space(1))) gv_t;
typedef void __attribute__((address_space(3))) lv_t;

#define GL16(g, l) __builtin_amdgcn_global_load_lds((gv_t*)(g), (lv_t*)(l), 16, 0, 0)

__device__ __forceinline__ unsigned short f2bf(float f) {
    unsigned int u = __float_as_uint(f);
    u += 0x7fffu + ((u >> 16) & 1u);
    return (unsigned short)(u >> 16);
}

// ---------- kernel 1: fused prepass: W int4-qdq -> bf16 ; x f32 -> bf16 ------
__global__ void __launch_bounds__(256) prep(const float* __restrict__ w,
                                            const float* __restrict__ x,
                                            unsigned short* __restrict__ wb,
                                            unsigned short* __restrict__ xb,
                                            int ng_w, int n8_x) {
    int id = blockIdx.x * 256 + threadIdx.x;
    if (id < ng_w) {
        const float4* p = (const float4*)w + (size_t)id * 2;
        float4 v0 = p[0], v1 = p[1];
        float t[8] = {v0.x, v0.y, v0.z, v0.w, v1.x, v1.y, v1.z, v1.w};
        float amax = 0.0f;
#pragma unroll
        for (int j = 0; j < 8; ++j) amax = fmaxf(amax, fabsf(t[j]));
        float scale = fmaxf(amax / 7.0f, 1e-8f);
        ushort8 o;
#pragma unroll
        for (int j = 0; j < 8; ++j) {
            float q = rintf(t[j] / scale);
            q = fminf(fmaxf(q, -7.0f), 7.0f);
            o[j] = f2bf(q * scale);
        }
        *((ushort8*)wb + id) = o;
    } else {
        int i = id - ng_w;
        if (i < n8_x) {
            const float4* p = (const float4*)x + (size_t)i * 2;
            float4 v0 = p[0], v1 = p[1];
            ushort8 o;
            o[0] = f2bf(v0.x); o[1] = f2bf(v0.y); o[2] = f2bf(v0.z); o[3] = f2bf(v0.w);
            o[4] = f2bf(v1.x); o[5] = f2bf(v1.y); o[6] = f2bf(v1.z); o[7] = f2bf(v1.w);
            *((ushort8*)xb + i) = o;
        }
    }
}

// ---------- kernel 2: 256x256 8-wave 8-phase GEMM with 32x32x16 MFMA ----------
// R6 schedule (m201-faithful phases, counted VM at ph4/8) with the MFMA shape
// switched to 32x32x16 (ceiling 2495 vs 2075 TF). Same fragment bytes, same
// read counts, same acc budget; C/D map: col=lane&31, row=(reg&3)+8*(reg>>2)
// +4*(lane>>5)  [m74/m101].
#define BM 256
#define BN 256
#define BK 64

#define MFMA_Q32(qm, qn, AF, BF)                                               \
    __builtin_amdgcn_s_setprio(1);                                             \
    _Pragma("unroll")                                                          \
    for (int ks = 0; ks < 4; ++ks)                                             \
        _Pragma("unroll")                                                      \
        for (int mt = 0; mt < 2; ++mt)                                         \
            acc[(qm) * 2 + mt][qn] =                                           \
                __builtin_amdgcn_mfma_f32_32x32x16_bf16(                       \
                    AF[mt][ks], BF[ks], acc[(qm) * 2 + mt][qn], 0, 0, 0);      \
    __builtin_amdgcn_s_setprio(0);

#define STAGE_A(b, h, kk)                                                      \
    {                                                                          \
        GL16(gA + (size_t)((h) * 64 + srow) * K + (kk) + schunk,               \
             &sA[b][h][0] + sldso);                                            \
        GL16(gA + (size_t)((h) * 64 + 128 + srow) * K + (kk) + schunk,         \
             &sA[b][h][64 * BK] + sldso);                                      \
    }
#define STAGE_B(b, h, kk)                                                      \
    {                                                                          \
        GL16(gB + (size_t)((h) * 32 + brow) * K + (kk) + schunk,               \
             &sB[b][h][0] + sldso);                                            \
        GL16(gB + (size_t)((h) * 32 + 128 + brow) * K + (kk) + schunk,         \
             &sB[b][h][64 * BK] + sldso);                                      \
    }

// A-frag (32 rows x 16 k): lane holds A[row=l&31][k=(l>>5)*8+j]; 1 b128/frag
#define READ_A32(dst, b, h)                                                    \
    _Pragma("unroll")                                                          \
    for (int mt = 0; mt < 2; ++mt)                                             \
        _Pragma("unroll")                                                      \
        for (int ks = 0; ks < 4; ++ks)                                         \
            dst[mt][ks] = *(const bf16x8*)                                     \
                &sA[b][h][(wr * 64 + mt * 32 + l31) * BK + e32[ks]];
#define READ_B32(dst, b, h)                                                    \
    _Pragma("unroll")                                                          \
    for (int ks = 0; ks < 4; ++ks)                                             \
        dst[ks] = *(const bf16x8*)&sB[b][h][(bcol + l31) * BK + e32[ks]];

#define BAR_()     asm volatile("s_barrier" ::: "memory")
#define VM_(n)     asm volatile("s_waitcnt vmcnt(" #n ")" ::: "memory")
#define LGKM_(n)   asm volatile("s_waitcnt lgkmcnt(" #n ")" ::: "memory")
#define SCHEDBAR() __builtin_amdgcn_sched_barrier(0)

#define PHASE(RDS, STG, QM, QN, AF, BF, HINT, VMQ)                             \
    {                                                                          \
        RDS;                                                                   \
        STG;                                                                   \
        HINT;                                                                  \
        BAR_();                                                                \
        LGKM_(0);                                                              \
        SCHEDBAR();                                                            \
        MFMA_Q32(QM, QN, AF, BF);                                              \
        VMQ;                                                                   \
        BAR_();                                                                \
    }

__global__ void __launch_bounds__(512, 2)
gemm256(const unsigned short* __restrict__ A,   // [M][K] bf16 bits (x)
        const unsigned short* __restrict__ B,   // [N][K] bf16 bits (w_deq)
        const float* __restrict__ bias,
        float* __restrict__ C,
        int M, int N, int K) {
    __shared__ unsigned short sA[2][2][128 * BK];
    __shared__ unsigned short sB[2][2][128 * BK];

    const int t   = threadIdx.x;
    const int w   = t >> 6;
    const int ln  = t & 63;
    const int l31 = ln & 31;
    const int lk5 = ln >> 5;
    const int l7  = ln & 7;
    const int wr  = w >> 2;                            // wave M index (128 rows)
    const int wc  = w & 3;                             // wave N index (64 cols)
    const int bcol = (wc >> 1) * 64 + (wc & 1) * 32;   // B slot base

    // T1: bijective XCD swizzle (gridDim.x % 8 == 0 here)
    const int nbn = N / BN;
    const int bid = blockIdx.x;
    const int swz = ((int)gridDim.x & 7) ? bid
                  : ((bid & 7) * ((int)gridDim.x >> 3) + (bid >> 3));
    const int m0 = (swz / nbn) * BM;
    const int n0 = (swz % nbn) * BN;

    const unsigned short* gA = A + (size_t)m0 * K;
    const unsigned short* gB = B + (size_t)n0 * K;

    const int srow   = t >> 3;
    const int brow   = (srow & 31) + ((srow >> 5) << 6);
    const int schunk = (((t & 7) ^ (srow & 7)) << 3);
    const int sldso  = (w * 8) * BK;

    // swizzled read element offsets: chunk (ks*2 + lane>>5) XOR row&7 (= l7)
    int e32[4];
#pragma unroll
    for (int ks = 0; ks < 4; ++ks)
        e32[ks] = (((ks * 2 + lk5) ^ l7) << 3);

    f32x16 acc[4][2];
#pragma unroll
    for (int i = 0; i < 4; ++i)
#pragma unroll
        for (int j = 0; j < 2; ++j)
            acc[i][j] = (f32x16)(0.0f);

    const int NT = K / BK;   // even
    const int J  = NT / 2;

    bf16x8 a0f[2][4], a1f[2][4], b0f[4], b1f[4];

    // prologue: buf0 = tile0 (4 halves), then buf1.h0 = tile1
    STAGE_A(0, 0, 0);
    STAGE_B(0, 0, 0);
    STAGE_A(0, 1, 0);
    STAGE_B(0, 1, 0);
    STAGE_A(1, 0, BK);
    STAGE_B(1, 0, BK);
    VM_(4);            // buf0 complete; buf1.h0 pair stays in flight
    BAR_();

    for (int it = 0; it < J; ++it) {
        const int t0 = 2 * it;
        const int k1 = (t0 + 1) * BK;
        int k2 = (t0 + 2) * BK;  if (k2 >= K) k2 = 0;   // clamped: dead data
        int k3 = (t0 + 3) * BK;  if (k3 >= K) k3 = 0;

        // ph1: read a0,b0 (buf0.h0); stage buf1.Ah1[t0+1]; Q00
        PHASE(READ_A32(a0f, 0, 0); READ_B32(b0f, 0, 0),
              STAGE_A(1, 1, k1), 0, 0, a0f, b0f, LGKM_(8), );
        // ph2: read a1 (buf0.h1); stage buf1.Bh1[t0+1]; Q10
        PHASE(READ_A32(a1f, 0, 1),
              STAGE_B(1, 1, k1), 1, 0, a1f, b0f, , );
        // ph3: read b1 (buf0.h1); stage buf0.Ah0[t0+2]; Q11
        PHASE(READ_B32(b1f, 0, 1),
              STAGE_A(0, 0, k2), 1, 1, a1f, b1f, , );
        // ph4: stage buf0.Bh0[t0+2]; Q01; counted gate
        PHASE(, STAGE_B(0, 0, k2), 0, 1, a0f, b1f, , VM_(4));

        // ph5-8: mirror on buf1
        PHASE(READ_A32(a0f, 1, 0); READ_B32(b0f, 1, 0),
              STAGE_A(0, 1, k2), 0, 0, a0f, b0f, LGKM_(8), );
        PHASE(READ_A32(a1f, 1, 1),
              STAGE_B(0, 1, k2), 1, 0, a1f, b0f, , );
        PHASE(READ_B32(b1f, 1, 1),
              STAGE_A(1, 0, k3), 1, 1, a1f, b1f, , );
        PHASE(, STAGE_B(1, 0, k3), 0, 1, a0f, b1f, , VM_(4));
    }
    VM_(0);   // drain in-flight LDS-DMA before exit (clamped tail stages)

    // epilogue: 32x32 C/D layout: col=lane&31, row=(reg&3)+8*(reg>>2)+4*(lane>>5)
#pragma unroll
    for (int qn = 0; qn < 2; ++qn) {
        const int n = n0 + wc * 64 + qn * 32 + l31;
        const float bv = bias[n];
#pragma unroll
        for (int i = 0; i < 4; ++i) {
            const int mb = m0 + wr * 128 + (i >> 1) * 64 + (i & 1) * 32 + lk5 * 4;
            f32x16 v = acc[i][qn];
#pragma unroll
            for (int rq = 0; rq < 4; ++rq)
#pragma unroll
                for (int rr = 0; rr < 4; ++rr)
                    C[(size_t)(mb + rq * 8 + rr) * N + n] = v[rq * 4 + rr] + bv;
        }
    }
}

// ---------- launcher ----------
extern "C" void kernel_launch(void* const* d_in, const int* in_sizes, int n_in,
                              void* d_out, int out_size, void* d_ws, size_t ws_size,
                              hipStream_t stream) {
    const float* x    = (const float*)d_in[0];
    const float* wgt  = (const float*)d_in[1];
    const float* bias = (const float*)d_in[2];
    float* out        = (float*)d_out;

    const int dout = in_sizes[2];            // 4096
    const int din  = in_sizes[1] / dout;     // 4096
    const int M    = in_sizes[0] / din;      // 8192
    const int N    = dout, K = din;

    unsigned short* xb = (unsigned short*)d_ws;          // [M][K] bf16 bits
    unsigned short* wb = xb + (size_t)M * K;             // [N][K] bf16 bits

    const int ng_w = (N * K) / 8;
    const int n8_x = (M * K) / 8;
    prep<<<(ng_w + n8_x + 255) / 256, 256, 0, stream>>>(wgt, x, wb, xb, ng_w, n8_x);

    const int nwg = (M / BM) * (N / BN);     // 512, % 8 == 0
    gemm256<<<nwg, 512, 0, stream>>>(xb, wb, bias, out, M, N, K);
}

// Round 11
// 309.989 us; speedup vs baseline: 1.3507x; 1.0392x over previous
//
#include <hip/hip_runtime.h>
#include <hip/hip_bf16.h>
#include <stdint.h>

// ---------- types ----------
typedef __attribute__((ext_vector_type(8))) __bf16 bf16x8;
typedef __attribute__((ext_vector_type(4))) float f32x4;
typedef __attribute__((ext_vector_type(8))) unsigned short ushort8;

typedef const void __attribute__((address_space(1))) gv_t;
typedef void __attribute__((address_space(3))) lv_t;

#define GL16(g, l) __builtin_amdgcn_global_load_lds((gv_t*)(g), (lv_t*)(l), 16, 0, 0)

__device__ __forceinline__ unsigned short f2bf(float f) {
    unsigned int u = __float_as_uint(f);
    u += 0x7fffu + ((u >> 16) & 1u);
    return (unsigned short)(u >> 16);
}

// ---------- kernel 1: fused prepass: W int4-qdq -> bf16 ; x f32 -> bf16 ------
__global__ void __launch_bounds__(256) prep(const float* __restrict__ w,
                                            const float* __restrict__ x,
                                            unsigned short* __restrict__ wb,
                                            unsigned short* __restrict__ xb,
                                            int ng_w, int n8_x) {
    int id = blockIdx.x * 256 + threadIdx.x;
    if (id < ng_w) {
        const float4* p = (const float4*)w + (size_t)id * 2;
        float4 v0 = p[0], v1 = p[1];
        float t[8] = {v0.x, v0.y, v0.z, v0.w, v1.x, v1.y, v1.z, v1.w};
        float amax = 0.0f;
#pragma unroll
        for (int j = 0; j < 8; ++j) amax = fmaxf(amax, fabsf(t[j]));
        float scale = fmaxf(amax / 7.0f, 1e-8f);
        ushort8 o;
#pragma unroll
        for (int j = 0; j < 8; ++j) {
            float q = rintf(t[j] / scale);
            q = fminf(fmaxf(q, -7.0f), 7.0f);
            o[j] = f2bf(q * scale);
        }
        *((ushort8*)wb + id) = o;
    } else {
        int i = id - ng_w;
        if (i < n8_x) {
            const float4* p = (const float4*)x + (size_t)i * 2;
            float4 v0 = p[0], v1 = p[1];
            ushort8 o;
            o[0] = f2bf(v0.x); o[1] = f2bf(v0.y); o[2] = f2bf(v0.z); o[3] = f2bf(v0.w);
            o[4] = f2bf(v1.x); o[5] = f2bf(v1.y); o[6] = f2bf(v1.z); o[7] = f2bf(v1.w);
            *((ushort8*)xb + i) = o;
        }
    }
}

// ---------- kernel 2: 256x256 8-wave LOOSE-SYNC bf16 GEMM ---------------------
// ONE barrier per K-tile; no intra-tile fences. The whole tile is a single
// compiler scheduling region: fine-grained lgkmcnt interleave (in-wave) plus
// up-to-a-tile wave skew (cross-wave, m114) overlap LDS traffic with MFMA.
// Stage targets buf^1 (WAR-free); tile-end lgkm(0)/vmcnt(0) are ~free (issued
// thousands of cycles earlier); then the single s_barrier.
#define BM 256
#define BN 256
#define BK 64

#define BAR_()   asm volatile("s_barrier" ::: "memory")
#define VM0_()   asm volatile("s_waitcnt vmcnt(0)" ::: "memory")
#define LGKM0_() asm volatile("s_waitcnt lgkmcnt(0)" ::: "memory")

#define STAGE_A(b, h, kk)                                                      \
    {                                                                          \
        GL16(gA + (size_t)((h) * 64 + srow) * K + (kk) + schunk,               \
             &sA[b][h][0] + sldso);                                            \
        GL16(gA + (size_t)((h) * 64 + 128 + srow) * K + (kk) + schunk,         \
             &sA[b][h][64 * BK] + sldso);                                      \
    }
#define STAGE_B(b, h, kk)                                                      \
    {                                                                          \
        GL16(gB + (size_t)((h) * 32 + brow) * K + (kk) + schunk,               \
             &sB[b][h][0] + sldso);                                            \
        GL16(gB + (size_t)((h) * 32 + 128 + brow) * K + (kk) + schunk,         \
             &sB[b][h][64 * BK] + sldso);                                      \
    }

// per-k-substep fragment reads (ks in {0,1}, K=32 each)
#define READ_A_KS(dst, b, h, ks)                                               \
    _Pragma("unroll")                                                          \
    for (int mi = 0; mi < 4; ++mi)                                             \
        dst[mi] = *(const bf16x8*)&sA[b][h][(wr * 64 + mi * 16 + lr) * BK + eks[ks]];
#define READ_B_KS(dst, b, h, ks)                                               \
    _Pragma("unroll")                                                          \
    for (int ni = 0; ni < 2; ++ni)                                             \
        dst[ni] = *(const bf16x8*)&sB[b][h][(bcol + ni * 16 + lr) * BK + eks[ks]];

// 32 MFMA: full wave-tile (128x64) for one k-substep
#define MFMA_KS(AL, AH, BL, BH)                                                \
    __builtin_amdgcn_s_setprio(1);                                             \
    _Pragma("unroll")                                                          \
    for (int mi = 0; mi < 4; ++mi)                                             \
        _Pragma("unroll")                                                      \
        for (int ni = 0; ni < 2; ++ni) {                                       \
            acc[mi][ni]     = __builtin_amdgcn_mfma_f32_16x16x32_bf16(         \
                AL[mi], BL[ni], acc[mi][ni], 0, 0, 0);                         \
            acc[mi][2 + ni] = __builtin_amdgcn_mfma_f32_16x16x32_bf16(         \
                AL[mi], BH[ni], acc[mi][2 + ni], 0, 0, 0);                     \
            acc[4 + mi][ni] = __builtin_amdgcn_mfma_f32_16x16x32_bf16(         \
                AH[mi], BL[ni], acc[4 + mi][ni], 0, 0, 0);                     \
            acc[4 + mi][2 + ni] = __builtin_amdgcn_mfma_f32_16x16x32_bf16(     \
                AH[mi], BH[ni], acc[4 + mi][2 + ni], 0, 0, 0);                 \
        }                                                                      \
    __builtin_amdgcn_s_setprio(0);

__global__ void __launch_bounds__(512, 2)
gemm256(const unsigned short* __restrict__ A,   // [M][K] bf16 bits (x)
        const unsigned short* __restrict__ B,   // [N][K] bf16 bits (w_deq)
        const float* __restrict__ bias,
        float* __restrict__ C,
        int M, int N, int K) {
    __shared__ unsigned short sA[2][2][128 * BK];
    __shared__ unsigned short sB[2][2][128 * BK];

    const int t  = threadIdx.x;
    const int w  = t >> 6;
    const int ln = t & 63;
    const int lr = ln & 15;
    const int lk = ln >> 4;
    const int wr = w >> 2;                             // wave M index (128 rows)
    const int wc = w & 3;                              // wave N index (64 cols)
    const int bcol = (wc >> 1) * 64 + (wc & 1) * 32;   // B slot base

    // T1: bijective XCD swizzle (gridDim.x % 8 == 0 here)
    const int nbn = N / BN;
    const int bid = blockIdx.x;
    const int swz = ((int)gridDim.x & 7) ? bid
                  : ((bid & 7) * ((int)gridDim.x >> 3) + (bid >> 3));
    const int m0 = (swz / nbn) * BM;
    const int n0 = (swz % nbn) * BN;

    const unsigned short* gA = A + (size_t)m0 * K;
    const unsigned short* gB = B + (size_t)n0 * K;

    const int srow   = t >> 3;
    const int brow   = (srow & 31) + ((srow >> 5) << 6);
    const int schunk = (((t & 7) ^ (srow & 7)) << 3);
    const int sldso  = (w * 8) * BK;

    // swizzled read element offsets per k-substep: chunk (ks*4+lk) XOR row&7
    int eks[2];
#pragma unroll
    for (int ks = 0; ks < 2; ++ks)
        eks[ks] = (((ks * 4 + lk) ^ (lr & 7)) << 3);

    f32x4 acc[8][4];
#pragma unroll
    for (int i = 0; i < 8; ++i)
#pragma unroll
        for (int j = 0; j < 4; ++j)
            acc[i][j] = (f32x4)(0.0f);

    const int NT = K / BK;   // 64

    // prologue: tile 0 -> buf 0
    STAGE_A(0, 0, 0); STAGE_A(0, 1, 0);
    STAGE_B(0, 0, 0); STAGE_B(0, 1, 0);
    VM0_();
    BAR_();

    bf16x8 al[4], ah[4], bl[2], bh[2];
    bf16x8 al1[4], ah1[4], bl1[2], bh1[2];

    for (int tt = 0; tt < NT; ++tt) {
        const int cur = tt & 1;
        const int nxt = cur ^ 1;

        // stage next tile first: 8 gload_lds fill the vm queue, land ~3000cyc later
        if (tt + 1 < NT) {
            const int kk = (tt + 1) * BK;
            STAGE_A(nxt, 0, kk); STAGE_A(nxt, 1, kk);
            STAGE_B(nxt, 0, kk); STAGE_B(nxt, 1, kk);
        }

        // ks=0 frags, then ks=1 frags, then MFMA clusters; no fences — the
        // compiler's counted lgkm waits let early MFMAs run under late reads.
        READ_A_KS(al, cur, 0, 0); READ_A_KS(ah, cur, 1, 0);
        READ_B_KS(bl, cur, 0, 0); READ_B_KS(bh, cur, 1, 0);
        READ_A_KS(al1, cur, 0, 1); READ_A_KS(ah1, cur, 1, 1);
        READ_B_KS(bl1, cur, 0, 1); READ_B_KS(bh1, cur, 1, 1);

        MFMA_KS(al, ah, bl, bh);
        MFMA_KS(al1, ah1, bl1, bh1);

        LGKM0_();   // reads drained (last MFMA already waited on them) — ~free
        VM0_();     // next tile landed (issued at loop top) — ~free
        BAR_();     // the ONLY barrier per K-tile
    }

    // epilogue: C/D layout col = lane&15, row = (lane>>4)*4 + reg
#pragma unroll
    for (int j = 0; j < 4; ++j) {
        const int n = n0 + wc * 64 + (j >> 1) * 32 + (j & 1) * 16 + lr;
        const float bv = bias[n];
#pragma unroll
        for (int i = 0; i < 8; ++i) {
            const int m = m0 + wr * 128 + (i >> 2) * 64 + (i & 3) * 16 + lk * 4;
            f32x4 v = acc[i][j];
            C[(size_t)(m + 0) * N + n] = v[0] + bv;
            C[(size_t)(m + 1) * N + n] = v[1] + bv;
            C[(size_t)(m + 2) * N + n] = v[2] + bv;
            C[(size_t)(m + 3) * N + n] = v[3] + bv;
        }
    }
}

// ---------- launcher ----------
extern "C" void kernel_launch(void* const* d_in, const int* in_sizes, int n_in,
                              void* d_out, int out_size, void* d_ws, size_t ws_size,
                              hipStream_t stream) {
    const float* x    = (const float*)d_in[0];
    const float* wgt  = (const float*)d_in[1];
    const float* bias = (const float*)d_in[2];
    float* out        = (float*)d_out;

    const int dout = in_sizes[2];            // 4096
    const int din  = in_sizes[1] / dout;     // 4096
    const int M    = in_sizes[0] / din;      // 8192
    const int N    = dout, K = din;

    unsigned short* xb = (unsigned short*)d_ws;          // [M][K] bf16 bits
    unsigned short* wb = xb + (size_t)M * K;             // [N][K] bf16 bits

    const int ng_w = (N * K) / 8;
    const int n8_x = (M * K) / 8;
    prep<<<(ng_w + n8_x + 255) / 256, 256, 0, stream>>>(wgt, x, wb, xb, ng_w, n8_x);

    const int nwg = (M / BM) * (N / BN);     // 512, % 8 == 0
    gemm256<<<nwg, 512, 0, stream>>>(xb, wb, bias, out, M, N, K);
}